// Round 1
// baseline (1261.754 us; speedup 1.0000x reference)
//
#include <hip/hip_runtime.h>

#define GCN_N 100000
#define GCN_E 640000
#define GCN_F 128

// ---------------------------------------------------------------- degree count
__global__ void count_deg(const int* __restrict__ cols, int* __restrict__ cnt, int E) {
    int e = blockIdx.x * 256 + threadIdx.x;
    if (e < E) atomicAdd(&cnt[cols[e]], 1);
}

// ---------------------------------------------------------------- dinv = rsqrt(deg)
__global__ void calc_dinv(const int* __restrict__ cnt, float* __restrict__ dinv, int N) {
    int i = blockIdx.x * 256 + threadIdx.x;
    if (i < N) dinv[i] = rsqrtf(2.0f + (float)cnt[i]);  // improved: self-loop weight 2.0
}

// ---------------------------------------------------------------- agg init with self-loop term
// agg[i][:] = 2*dinv[i]^2 * x[i][:]   (plain stores; replaces memset + self-loop atomics)
__global__ void agg_init(const float* __restrict__ x, const float* __restrict__ dinv,
                         float* __restrict__ agg, int N) {
    int i = blockIdx.x * 256 + threadIdx.x;        // float4 index, 32 per node
    int total = N * (GCN_F / 4);
    if (i >= total) return;
    int node = i >> 5;
    float d = dinv[node];
    float w = 2.0f * d * d;
    float4 v = ((const float4*)x)[i];
    v.x *= w; v.y *= w; v.z *= w; v.w *= w;
    ((float4*)agg)[i] = v;
}

// ---------------------------------------------------------------- edge scatter (atomics)
// 32 lanes per edge, float4 per lane. agg[col] += dinv[row]*dinv[col]*x[row]
__global__ __launch_bounds__(256) void edge_scatter(
        const float* __restrict__ x, const int* __restrict__ rows,
        const int* __restrict__ cols, const float* __restrict__ dinv,
        float* __restrict__ agg, int E) {
    int sub  = threadIdx.x >> 5;                   // 8 edges per block
    int lane = threadIdx.x & 31;
    int e = blockIdx.x * 8 + sub;
    if (e >= E) return;
    int r = rows[e];
    int c = cols[e];
    float w = dinv[r] * dinv[c];
    float4 v = ((const float4*)(x + (size_t)r * GCN_F))[lane];
    float* dst = agg + (size_t)c * GCN_F + lane * 4;
    unsafeAtomicAdd(dst + 0, w * v.x);
    unsafeAtomicAdd(dst + 1, w * v.y);
    unsafeAtomicAdd(dst + 2, w * v.z);
    unsafeAtomicAdd(dst + 3, w * v.w);
}

// ---------------------------------------------------------------- out = agg @ W + b
// 64-row tile in LDS (pad 128->132 floats), W from global (64KB, L1/L2 hot).
// 256 threads: thread = (rg = t>>5) row-group of 8 rows, (cg = t&31) col-group of 4 cols.
__global__ __launch_bounds__(256) void gemm_bias(
        const float* __restrict__ agg, const float* __restrict__ W,
        const float* __restrict__ b, float* __restrict__ out, int N) {
    __shared__ float As[64][132];                  // 33.8 KB -> 4 blocks/CU
    int t = threadIdx.x;
    int row0 = blockIdx.x * 64;

    // stage A tile: 64 rows x 32 float4
    for (int i = t; i < 64 * 32; i += 256) {
        int rr = i >> 5, kk = i & 31;
        float4 v = make_float4(0.f, 0.f, 0.f, 0.f);
        int r = row0 + rr;
        if (r < N) v = ((const float4*)(agg + (size_t)r * GCN_F))[kk];
        *(float4*)&As[rr][kk * 4] = v;
    }
    __syncthreads();

    int cg = t & 31;   // cols cg*4 .. cg*4+3
    int rg = t >> 5;   // rows rg*8 .. rg*8+7

    float acc[8][4];
#pragma unroll
    for (int i = 0; i < 8; i++)
#pragma unroll
        for (int j = 0; j < 4; j++) acc[i][j] = 0.f;

    for (int k = 0; k < 128; k += 4) {
        float4 wv0 = *(const float4*)&W[(k + 0) * GCN_F + cg * 4];
        float4 wv1 = *(const float4*)&W[(k + 1) * GCN_F + cg * 4];
        float4 wv2 = *(const float4*)&W[(k + 2) * GCN_F + cg * 4];
        float4 wv3 = *(const float4*)&W[(k + 3) * GCN_F + cg * 4];
#pragma unroll
        for (int i = 0; i < 8; i++) {
            float4 av = *(const float4*)&As[rg * 8 + i][k];
            acc[i][0] += av.x * wv0.x + av.y * wv1.x + av.z * wv2.x + av.w * wv3.x;
            acc[i][1] += av.x * wv0.y + av.y * wv1.y + av.z * wv2.y + av.w * wv3.y;
            acc[i][2] += av.x * wv0.z + av.y * wv1.z + av.z * wv2.z + av.w * wv3.z;
            acc[i][3] += av.x * wv0.w + av.y * wv1.w + av.z * wv2.w + av.w * wv3.w;
        }
    }

    float4 bv = *(const float4*)&b[cg * 4];
#pragma unroll
    for (int i = 0; i < 8; i++) {
        int r = row0 + rg * 8 + i;
        if (r < N) {
            float4 o;
            o.x = acc[i][0] + bv.x; o.y = acc[i][1] + bv.y;
            o.z = acc[i][2] + bv.z; o.w = acc[i][3] + bv.w;
            *(float4*)&out[(size_t)r * GCN_F + cg * 4] = o;
        }
    }
}

// ---------------------------------------------------------------- launch
extern "C" void kernel_launch(void* const* d_in, const int* in_sizes, int n_in,
                              void* d_out, int out_size, void* d_ws, size_t ws_size,
                              hipStream_t stream) {
    const float* x  = (const float*)d_in[0];
    const int*   ei = (const int*)d_in[1];     // [2, E]: rows then cols
    const float* W  = (const float*)d_in[2];
    const float* b  = (const float*)d_in[3];
    float* out = (float*)d_out;

    const int N = GCN_N, E = GCN_E;
    const int* rows = ei;
    const int* cols = ei + E;

    // workspace layout (512B aligned): cnt[N] int | dinv[N] float | agg[N*128] float
    char* ws = (char*)d_ws;
    int*   cnt  = (int*)ws;
    float* dinv = (float*)(ws + 401408);               // 100000*4 rounded up
    float* agg  = (float*)(ws + 802816);               // 51.2 MB

    hipMemsetAsync(cnt, 0, (size_t)N * sizeof(int), stream);

    count_deg<<<(E + 255) / 256, 256, 0, stream>>>(cols, cnt, E);
    calc_dinv<<<(N + 255) / 256, 256, 0, stream>>>(cnt, dinv, N);
    agg_init<<<(N * 32 + 255) / 256, 256, 0, stream>>>(x, dinv, agg, N);
    edge_scatter<<<(E + 7) / 8, 256, 0, stream>>>(x, rows, cols, dinv, agg, E);
    gemm_bias<<<(N + 63) / 64, 256, 0, stream>>>(agg, W, b, out, N);
}

// Round 2
// 279.304 us; speedup vs baseline: 4.5175x; 4.5175x over previous
//
#include <hip/hip_runtime.h>

#define GCN_N 100000
#define GCN_E 640000
#define GCN_F 128

// ---------------------------------------------------------------- degree count (by destination)
__global__ void count_deg(const int* __restrict__ cols, int* __restrict__ cnt, int E) {
    int e = blockIdx.x * 256 + threadIdx.x;
    if (e < E) atomicAdd(&cnt[cols[e]], 1);
}

// ---------------------------------------------------------------- dinv = rsqrt(2 + deg)
__global__ void calc_dinv(const int* __restrict__ cnt, float* __restrict__ dinv, int N) {
    int i = blockIdx.x * 256 + threadIdx.x;
    if (i < N) dinv[i] = rsqrtf(2.0f + (float)cnt[i]);  // improved: self-loop weight 2.0
}

// ---------------------------------------------------------------- scan step 1: per-block sums
__global__ void scan1(const int* __restrict__ cnt, int* __restrict__ bsum, int N) {
    __shared__ int s[256];
    int t = threadIdx.x;
    int i = blockIdx.x * 256 + t;
    s[t] = (i < N) ? cnt[i] : 0;
    __syncthreads();
    for (int o = 128; o > 0; o >>= 1) {
        if (t < o) s[t] += s[t + o];
        __syncthreads();
    }
    if (t == 0) bsum[blockIdx.x] = s[0];
}

// ---------------------------------------------------------------- scan step 2: scan the 391 partials (1 block)
__global__ void scan2(const int* __restrict__ bsum, int* __restrict__ bpre,
                      int NB, int* __restrict__ offs, int N, int E) {
    __shared__ int s[512];
    int t = threadIdx.x;
    int v0 = (t < NB) ? bsum[t] : 0;
    s[t] = v0;
    __syncthreads();
    for (int o = 1; o < 512; o <<= 1) {
        int tmp = (t >= o) ? s[t - o] : 0;
        __syncthreads();
        s[t] += tmp;
        __syncthreads();
    }
    if (t < NB) bpre[t] = s[t] - v0;   // exclusive
    if (t == 0) offs[N] = E;           // sentinel
}

// ---------------------------------------------------------------- scan step 3: final offsets + cursors
__global__ void scan3(const int* __restrict__ cnt, const int* __restrict__ bpre,
                      int* __restrict__ offs, int* __restrict__ cur, int N) {
    __shared__ int s[256];
    int t = threadIdx.x;
    int i = blockIdx.x * 256 + t;
    int v0 = (i < N) ? cnt[i] : 0;
    s[t] = v0;
    __syncthreads();
    for (int o = 1; o < 256; o <<= 1) {
        int tmp = (t >= o) ? s[t - o] : 0;
        __syncthreads();
        s[t] += tmp;
        __syncthreads();
    }
    if (i < N) {
        int excl = s[t] - v0 + bpre[blockIdx.x];
        offs[i] = excl;
        cur[i]  = excl;
    }
}

// ---------------------------------------------------------------- CSR bucket fill (int atomics only)
__global__ void fill_csr(const int* __restrict__ rows, const int* __restrict__ cols,
                         int* __restrict__ cur, int* __restrict__ srt, int E) {
    int e = blockIdx.x * 256 + threadIdx.x;
    if (e < E) {
        int d = atomicAdd(&cur[cols[e]], 1);
        srt[d] = rows[e];
    }
}

// ---------------------------------------------------------------- fused gather + GEMM + bias
// Block = 256 threads = 8 groups of 32 lanes; handles 64 nodes.
// Phase 1: each group aggregates one node row (float4/lane) incl. self-loop -> LDS.
// Phase 2: register-tiled GEMM out[64x128] = As[64x128] @ W + b.
__global__ __launch_bounds__(256) void gcn_fused(
        const float* __restrict__ x, const int* __restrict__ offs,
        const int* __restrict__ srt, const float* __restrict__ dinv,
        const float* __restrict__ W, const float* __restrict__ b,
        float* __restrict__ out, int N) {
    __shared__ float As[64][132];                  // 33.8 KB
    int t = threadIdx.x;
    int lane = t & 31;
    int sub  = t >> 5;
    int row0 = blockIdx.x * 64;

    // ---- phase 1: aggregate 8 rows per rep, 8 reps = 64 rows
    for (int rep = 0; rep < 8; ++rep) {
        int c = row0 + rep * 8 + sub;
        float4 acc = make_float4(0.f, 0.f, 0.f, 0.f);
        if (c < N) {
            float dc = dinv[c];
            float w0 = 2.0f * dc * dc;             // improved self-loop
            float4 xv = ((const float4*)(x + (size_t)c * GCN_F))[lane];
            acc.x = w0 * xv.x; acc.y = w0 * xv.y;
            acc.z = w0 * xv.z; acc.w = w0 * xv.w;
            int j0 = offs[c], j1 = offs[c + 1];
            int j = j0;
            while (j < j1) {
                int m = j1 - j; if (m > 32) m = 32;
                // lanes cooperatively load up to 32 edge sources + weights
                int   r_l = (lane < m) ? srt[j + lane] : 0;
                float w_l = (lane < m) ? dinv[r_l] * dc : 0.f;
                for (int i = 0; i < m; ++i) {
                    int   r = __shfl(r_l, i, 32);
                    float w = __shfl(w_l, i, 32);
                    float4 v = ((const float4*)(x + (size_t)r * GCN_F))[lane];
                    acc.x += w * v.x; acc.y += w * v.y;
                    acc.z += w * v.z; acc.w += w * v.w;
                }
                j += m;
            }
        }
        *(float4*)&As[rep * 8 + sub][lane * 4] = acc;
    }
    __syncthreads();

    // ---- phase 2: GEMM + bias
    int cg = t & 31;   // cols cg*4 .. cg*4+3
    int rg = t >> 5;   // rows rg*8 .. rg*8+7

    float acc[8][4];
#pragma unroll
    for (int i = 0; i < 8; i++)
#pragma unroll
        for (int j = 0; j < 4; j++) acc[i][j] = 0.f;

    for (int k = 0; k < 128; k += 4) {
        float4 wv0 = *(const float4*)&W[(k + 0) * GCN_F + cg * 4];
        float4 wv1 = *(const float4*)&W[(k + 1) * GCN_F + cg * 4];
        float4 wv2 = *(const float4*)&W[(k + 2) * GCN_F + cg * 4];
        float4 wv3 = *(const float4*)&W[(k + 3) * GCN_F + cg * 4];
#pragma unroll
        for (int i = 0; i < 8; i++) {
            float4 av = *(const float4*)&As[rg * 8 + i][k];
            acc[i][0] += av.x * wv0.x + av.y * wv1.x + av.z * wv2.x + av.w * wv3.x;
            acc[i][1] += av.x * wv0.y + av.y * wv1.y + av.z * wv2.y + av.w * wv3.y;
            acc[i][2] += av.x * wv0.z + av.y * wv1.z + av.z * wv2.z + av.w * wv3.z;
            acc[i][3] += av.x * wv0.w + av.y * wv1.w + av.z * wv2.w + av.w * wv3.w;
        }
    }

    float4 bv = *(const float4*)&b[cg * 4];
#pragma unroll
    for (int i = 0; i < 8; i++) {
        int r = row0 + rg * 8 + i;
        if (r < N) {
            float4 o;
            o.x = acc[i][0] + bv.x; o.y = acc[i][1] + bv.y;
            o.z = acc[i][2] + bv.z; o.w = acc[i][3] + bv.w;
            *(float4*)&out[(size_t)r * GCN_F + cg * 4] = o;
        }
    }
}

// ---------------------------------------------------------------- launch
extern "C" void kernel_launch(void* const* d_in, const int* in_sizes, int n_in,
                              void* d_out, int out_size, void* d_ws, size_t ws_size,
                              hipStream_t stream) {
    const float* x  = (const float*)d_in[0];
    const int*   ei = (const int*)d_in[1];     // [2, E]: rows then cols
    const float* W  = (const float*)d_in[2];
    const float* b  = (const float*)d_in[3];
    float* out = (float*)d_out;

    const int N = GCN_N, E = GCN_E;
    const int* rows = ei;
    const int* cols = ei + E;

    // workspace layout (~4.2 MB total)
    char* ws = (char*)d_ws;
    int*   cnt  = (int*)(ws + 0);              // N ints
    float* dinv = (float*)(ws + 400000);       // N floats
    int*   offs = (int*)(ws + 800000);         // N+1 ints
    int*   cur  = (int*)(ws + 1200064);        // N ints
    int*   srt  = (int*)(ws + 1600064);        // E ints
    int*   bsum = (int*)(ws + 4160064);        // 391 ints
    int*   bpre = (int*)(ws + 4161728);        // 391 ints

    const int NB = (N + 255) / 256;            // 391 scan blocks

    hipMemsetAsync(cnt, 0, (size_t)N * sizeof(int), stream);

    count_deg<<<(E + 255) / 256, 256, 0, stream>>>(cols, cnt, E);
    calc_dinv<<<NB, 256, 0, stream>>>(cnt, dinv, N);
    scan1<<<NB, 256, 0, stream>>>(cnt, bsum, N);
    scan2<<<1, 512, 0, stream>>>(bsum, bpre, NB, offs, N, E);
    scan3<<<NB, 256, 0, stream>>>(cnt, bpre, offs, cur, N);
    fill_csr<<<(E + 255) / 256, 256, 0, stream>>>(rows, cols, cur, srt, E);
    gcn_fused<<<(N + 63) / 64, 256, 0, stream>>>(x, offs, srt, dinv, W, b, out, N);
}

// Round 3
// 263.952 us; speedup vs baseline: 4.7802x; 1.0582x over previous
//
#include <hip/hip_runtime.h>

#define GCN_N 100000
#define GCN_E 640000
#define GCN_F 128

// ---------------------------------------------------------------- degree count (by destination)
__global__ void count_deg(const int* __restrict__ cols, int* __restrict__ cnt, int E) {
    int e = blockIdx.x * 256 + threadIdx.x;
    if (e < E) atomicAdd(&cnt[cols[e]], 1);
}

// ---------------------------------------------------------------- dinv = rsqrt(2 + deg)
__global__ void calc_dinv(const int* __restrict__ cnt, float* __restrict__ dinv, int N) {
    int i = blockIdx.x * 256 + threadIdx.x;
    if (i < N) dinv[i] = rsqrtf(2.0f + (float)cnt[i]);  // improved: self-loop weight 2.0
}

// ---------------------------------------------------------------- x -> bf16 (RNE), vectorized
__device__ inline unsigned short f2bf(float f) {
    unsigned u = __float_as_uint(f);
    return (unsigned short)((u + 0x7fff + ((u >> 16) & 1)) >> 16);
}
__global__ void x_to_bf16(const float* __restrict__ x, ushort* __restrict__ xb, int total4) {
    int i = blockIdx.x * 256 + threadIdx.x;
    if (i < total4) {
        float4 v = ((const float4*)x)[i];
        ushort4 o;
        o.x = f2bf(v.x); o.y = f2bf(v.y); o.z = f2bf(v.z); o.w = f2bf(v.w);
        ((ushort4*)xb)[i] = o;
    }
}

// ---------------------------------------------------------------- scan step 1: per-block sums
__global__ void scan1(const int* __restrict__ cnt, int* __restrict__ bsum, int N) {
    __shared__ int s[256];
    int t = threadIdx.x;
    int i = blockIdx.x * 256 + t;
    s[t] = (i < N) ? cnt[i] : 0;
    __syncthreads();
    for (int o = 128; o > 0; o >>= 1) {
        if (t < o) s[t] += s[t + o];
        __syncthreads();
    }
    if (t == 0) bsum[blockIdx.x] = s[0];
}

// ---------------------------------------------------------------- scan step 2: scan 391 partials (1 block)
__global__ void scan2(const int* __restrict__ bsum, int* __restrict__ bpre,
                      int NB, int* __restrict__ offs, int N, int E) {
    __shared__ int s[512];
    int t = threadIdx.x;
    int v0 = (t < NB) ? bsum[t] : 0;
    s[t] = v0;
    __syncthreads();
    for (int o = 1; o < 512; o <<= 1) {
        int tmp = (t >= o) ? s[t - o] : 0;
        __syncthreads();
        s[t] += tmp;
        __syncthreads();
    }
    if (t < NB) bpre[t] = s[t] - v0;   // exclusive
    if (t == 0) offs[N] = E;           // sentinel
}

// ---------------------------------------------------------------- scan step 3: final offsets + cursors
__global__ void scan3(const int* __restrict__ cnt, const int* __restrict__ bpre,
                      int* __restrict__ offs, int* __restrict__ cur, int N) {
    __shared__ int s[256];
    int t = threadIdx.x;
    int i = blockIdx.x * 256 + t;
    int v0 = (i < N) ? cnt[i] : 0;
    s[t] = v0;
    __syncthreads();
    for (int o = 1; o < 256; o <<= 1) {
        int tmp = (t >= o) ? s[t - o] : 0;
        __syncthreads();
        s[t] += tmp;
        __syncthreads();
    }
    if (i < N) {
        int excl = s[t] - v0 + bpre[blockIdx.x];
        offs[i] = excl;
        cur[i]  = excl;
    }
}

// ---------------------------------------------------------------- CSR fill + per-edge weight
__global__ void fill_csr(const int* __restrict__ rows, const int* __restrict__ cols,
                         const float* __restrict__ dinv, int* __restrict__ cur,
                         int* __restrict__ srt, float* __restrict__ wgt, int E) {
    int e = blockIdx.x * 256 + threadIdx.x;
    if (e < E) {
        int r = rows[e], c = cols[e];
        int d = atomicAdd(&cur[c], 1);
        srt[d] = r;
        wgt[d] = dinv[r] * dinv[c];
    }
}

// ---------------------------------------------------------------- fused gather(bf16) + GEMM + bias
// Block = 256 threads = 8 groups of 32 lanes; 64 nodes per block.
__global__ __launch_bounds__(256) void gcn_fused(
        const float* __restrict__ x, const ushort* __restrict__ xb,
        const int* __restrict__ offs, const int* __restrict__ srt,
        const float* __restrict__ wgt, const float* __restrict__ dinv,
        const float* __restrict__ W, const float* __restrict__ b,
        float* __restrict__ out, int N) {
    __shared__ float As[64][132];                  // 33.8 KB -> 4 blocks/CU
    int t = threadIdx.x;
    int lane = t & 31;
    int sub  = t >> 5;
    int row0 = blockIdx.x * 64;
    const ushort4* xb4 = (const ushort4*)xb;       // 32 ushort4 per row

    // ---- phase 1: aggregate (bf16 gather, 4-deep load pipeline)
    for (int rep = 0; rep < 8; ++rep) {
        int c = row0 + rep * 8 + sub;
        float4 acc = make_float4(0.f, 0.f, 0.f, 0.f);
        if (c < N) {
            float dc = dinv[c];
            float w0 = 2.0f * dc * dc;             // improved self-loop, fp32 x
            float4 xv = ((const float4*)(x + (size_t)c * GCN_F))[lane];
            acc.x = w0 * xv.x; acc.y = w0 * xv.y;
            acc.z = w0 * xv.z; acc.w = w0 * xv.w;
            int j0 = offs[c], j1 = offs[c + 1];
            for (int j = j0; j < j1; j += 32) {
                int m = j1 - j; if (m > 32) m = 32;
                int   r_l = (lane < m) ? srt[j + lane] : 0;   // pad: row 0
                float w_l = (lane < m) ? wgt[j + lane] : 0.f; // pad: weight 0
                int mm = (m + 3) & ~3;
                for (int i = 0; i < mm; i += 4) {
                    int r0 = __shfl(r_l, i + 0, 32), r1 = __shfl(r_l, i + 1, 32);
                    int r2 = __shfl(r_l, i + 2, 32), r3 = __shfl(r_l, i + 3, 32);
                    float w0_ = __shfl(w_l, i + 0, 32), w1_ = __shfl(w_l, i + 1, 32);
                    float w2_ = __shfl(w_l, i + 2, 32), w3_ = __shfl(w_l, i + 3, 32);
                    // 4 independent 8B gathers in flight
                    ushort4 v0 = xb4[(size_t)r0 * 32 + lane];
                    ushort4 v1 = xb4[(size_t)r1 * 32 + lane];
                    ushort4 v2 = xb4[(size_t)r2 * 32 + lane];
                    ushort4 v3 = xb4[(size_t)r3 * 32 + lane];
                    acc.x += w0_ * __uint_as_float((unsigned)v0.x << 16)
                           + w1_ * __uint_as_float((unsigned)v1.x << 16)
                           + w2_ * __uint_as_float((unsigned)v2.x << 16)
                           + w3_ * __uint_as_float((unsigned)v3.x << 16);
                    acc.y += w0_ * __uint_as_float((unsigned)v0.y << 16)
                           + w1_ * __uint_as_float((unsigned)v1.y << 16)
                           + w2_ * __uint_as_float((unsigned)v2.y << 16)
                           + w3_ * __uint_as_float((unsigned)v3.y << 16);
                    acc.z += w0_ * __uint_as_float((unsigned)v0.z << 16)
                           + w1_ * __uint_as_float((unsigned)v1.z << 16)
                           + w2_ * __uint_as_float((unsigned)v2.z << 16)
                           + w3_ * __uint_as_float((unsigned)v3.z << 16);
                    acc.w += w0_ * __uint_as_float((unsigned)v0.w << 16)
                           + w1_ * __uint_as_float((unsigned)v1.w << 16)
                           + w2_ * __uint_as_float((unsigned)v2.w << 16)
                           + w3_ * __uint_as_float((unsigned)v3.w << 16);
                }
            }
        }
        *(float4*)&As[rep * 8 + sub][lane * 4] = acc;
    }
    __syncthreads();

    // ---- phase 2: GEMM + bias
    int cg = t & 31;   // cols cg*4 .. cg*4+3
    int rg = t >> 5;   // rows rg*8 .. rg*8+7

    float acc[8][4];
#pragma unroll
    for (int i = 0; i < 8; i++)
#pragma unroll
        for (int j = 0; j < 4; j++) acc[i][j] = 0.f;

    for (int k = 0; k < 128; k += 4) {
        float4 wv0 = *(const float4*)&W[(k + 0) * GCN_F + cg * 4];
        float4 wv1 = *(const float4*)&W[(k + 1) * GCN_F + cg * 4];
        float4 wv2 = *(const float4*)&W[(k + 2) * GCN_F + cg * 4];
        float4 wv3 = *(const float4*)&W[(k + 3) * GCN_F + cg * 4];
#pragma unroll
        for (int i = 0; i < 8; i++) {
            float4 av = *(const float4*)&As[rg * 8 + i][k];
            acc[i][0] += av.x * wv0.x + av.y * wv1.x + av.z * wv2.x + av.w * wv3.x;
            acc[i][1] += av.x * wv0.y + av.y * wv1.y + av.z * wv2.y + av.w * wv3.y;
            acc[i][2] += av.x * wv0.z + av.y * wv1.z + av.z * wv2.z + av.w * wv3.z;
            acc[i][3] += av.x * wv0.w + av.y * wv1.w + av.z * wv2.w + av.w * wv3.w;
        }
    }

    float4 bv = *(const float4*)&b[cg * 4];
#pragma unroll
    for (int i = 0; i < 8; i++) {
        int r = row0 + rg * 8 + i;
        if (r < N) {
            float4 o;
            o.x = acc[i][0] + bv.x; o.y = acc[i][1] + bv.y;
            o.z = acc[i][2] + bv.z; o.w = acc[i][3] + bv.w;
            *(float4*)&out[(size_t)r * GCN_F + cg * 4] = o;
        }
    }
}

// ---------------------------------------------------------------- launch
extern "C" void kernel_launch(void* const* d_in, const int* in_sizes, int n_in,
                              void* d_out, int out_size, void* d_ws, size_t ws_size,
                              hipStream_t stream) {
    const float* x  = (const float*)d_in[0];
    const int*   ei = (const int*)d_in[1];     // [2, E]: rows then cols
    const float* W  = (const float*)d_in[2];
    const float* b  = (const float*)d_in[3];
    float* out = (float*)d_out;

    const int N = GCN_N, E = GCN_E;
    const int* rows = ei;
    const int* cols = ei + E;

    // workspace layout (~32 MB)
    char* ws = (char*)d_ws;
    int*    cnt  = (int*)(ws + 0);             // N ints
    float*  dinv = (float*)(ws + 400128);      // N floats
    int*    offs = (int*)(ws + 800256);        // N+1 ints
    int*    cur  = (int*)(ws + 1200384);       // N ints
    int*    srt  = (int*)(ws + 1600512);       // E ints
    float*  wgt  = (float*)(ws + 4160512);     // E floats
    int*    bsum = (int*)(ws + 6720512);       // 391 ints
    int*    bpre = (int*)(ws + 6722304);       // 391 ints
    ushort* xb   = (ushort*)(ws + 6724096);    // N*128 bf16 = 25.6 MB

    const int NB = (N + 255) / 256;            // 391 scan blocks

    hipMemsetAsync(cnt, 0, (size_t)N * sizeof(int), stream);

    count_deg<<<(E + 255) / 256, 256, 0, stream>>>(cols, cnt, E);
    x_to_bf16<<<(N * 32 + 255) / 256, 256, 0, stream>>>(x, xb, N * 32);
    calc_dinv<<<NB, 256, 0, stream>>>(cnt, dinv, N);
    scan1<<<NB, 256, 0, stream>>>(cnt, bsum, N);
    scan2<<<1, 512, 0, stream>>>(bsum, bpre, NB, offs, N, E);
    scan3<<<NB, 256, 0, stream>>>(cnt, bpre, offs, cur, N);
    fill_csr<<<(E + 255) / 256, 256, 0, stream>>>(rows, cols, dinv, cur, srt, wgt, E);
    gcn_fused<<<(N + 63) / 64, 256, 0, stream>>>(x, xb, offs, srt, wgt, dinv, W, b, out, N);
}